// Round 3
// baseline (10.460 us; speedup 1.0000x reference)
//
#include <hip/hip_runtime.h>

// P1 function-space evaluation on a regular 17x17 grid mesh over [0,1]^2.
// Direct cell location replaces the reference's 512-triangle scan.
// Vertex (i,j) -> weight index i*17+j, coord (i/16, j/16).
// Cell split: lower tri (v00,v10,v11) covers fy<=fx; upper (v00,v11,v01)
// covers fy>=fx. P1 interp is continuous so the diagonal tie is value-neutral.
//
// Reference boundary semantics: in_bb is STRICT and the 1e-10 bbox padding
// rounds away in float32 everywhere except at 0 — points lying EXACTLY on an
// interior grid line (x*16 or y*16 integer >= 1) are in no triangle's bbox
// and the reference outputs 0. x*16 is exact in f32 so we detect this exactly.
//
// R2: 4 points/thread (2x float4 load issued BEFORE the LDS weight stage so
// HBM latency hides under stage+barrier; 1x float4 coalesced store).
// 2048 blocks x 256 = 8192 waves = 32 waves/CU: full occupancy.

#define NW 289  // 17*17 weights

__device__ __forceinline__ float eval_pt(float x, float y, const float* __restrict__ ws) {
    float gx = x * 16.0f;
    float gy = y * 16.0f;
    int i0 = (int)gx;
    int j0 = (int)gy;
    bool boundary = ((float)i0 == gx && i0 >= 1) || ((float)j0 == gy && j0 >= 1);
    int i = min(i0, 15);
    int j = min(j0, 15);
    float fx = gx - (float)i;
    float fy = gy - (float)j;
    const float* wb = &ws[i * 17 + j];
    float w00 = wb[0];
    float w01 = wb[1];
    float w10 = wb[17];
    float w11 = wb[18];
    bool up = fy > fx;
    float s  = up ? fx      : fx - fy;
    float tt = up ? fy - fx : fy;
    float c1 = up ? w11     : w10;
    float c2 = up ? w01     : w11;
    float val = (1.0f - s - tt) * w00 + s * c1 + tt * c2;
    return boundary ? 0.0f : val;
}

__global__ __launch_bounds__(256) void p1_eval_kernel(
    const float4* __restrict__ x4,   // 2 points per float4
    const float*  __restrict__ w,    // 289 vertex weights
    float4*       __restrict__ out4, // 4 outputs per float4
    int n2)                          // count of float4-PAIRS (= out4 elements)
{
    __shared__ float ws[NW];

    int gid = blockIdx.x * 256 + threadIdx.x;
    bool valid = gid < n2;

    // Issue both x-loads first; their HBM latency hides under the weight
    // staging loop and the barrier.
    float4 va = make_float4(0.f, 0.f, 0.f, 0.f);
    float4 vb = va;
    if (valid) {
        va = x4[2 * gid];
        vb = x4[2 * gid + 1];
    }

    for (int k = threadIdx.x; k < NW; k += 256) ws[k] = w[k];
    __syncthreads();

    if (!valid) return;

    float4 r;
    r.x = eval_pt(va.x, va.y, ws);
    r.y = eval_pt(va.z, va.w, ws);
    r.z = eval_pt(vb.x, vb.y, ws);
    r.w = eval_pt(vb.z, vb.w, ws);
    out4[gid] = r;
}

extern "C" void kernel_launch(void* const* d_in, const int* in_sizes, int n_in,
                              void* d_out, int out_size, void* d_ws, size_t ws_size,
                              hipStream_t stream) {
    // inputs: x (8,262144,2) f32, weight (289,) f32, tri_A, Minv, bbox, dofs (unused)
    const float4* x4 = (const float4*)d_in[0];
    const float*  w  = (const float*)d_in[1];
    float4* out4 = (float4*)d_out;

    int n_floats = in_sizes[0];      // 8*262144*2 = 4,194,304
    int n4 = n_floats / 4;           // 1,048,576 float4s (2 points each)
    int n2 = n4 / 2;                 // 524,288 threads, 4 points each
    int blocks = (n2 + 255) / 256;   // 2048

    p1_eval_kernel<<<blocks, 256, 0, stream>>>(x4, w, out4, n2);
}

// Round 5
// 10.308 us; speedup vs baseline: 1.0147x; 1.0147x over previous
//
#include <hip/hip_runtime.h>

// P1 function-space evaluation on a regular 17x17 grid mesh over [0,1]^2.
// Direct cell location replaces the reference's 512-triangle scan.
// Vertex (i,j) -> weight index i*17+j, coord (i/16, j/16).
// Cell split: lower tri (v00,v10,v11) covers fy<=fx; upper (v00,v11,v01)
// covers fy>=fx. P1 interp is continuous so the diagonal tie is value-neutral.
//
// Reference boundary semantics: in_bb is STRICT and the 1e-10 bbox padding
// rounds away in float32 everywhere except at 0 — points lying EXACTLY on an
// interior grid line (x*16 or y*16 integer >= 1) are in no triangle's bbox
// and the reference outputs 0. x*16 is exact in f32 so we detect this exactly.
//
// R5 (= R4 with native vector types for the nontemporal builtins):
// (1) cell-packed LDS table cw[256]={w00,w01,w10,w11} -> one aligned
// ds_read_b128 per point instead of 4 scattered ds_read_b32; (2) w-loads
// issued before x-loads so staging overlaps HBM latency; (3) nontemporal
// streaming loads/stores (x and out are touched once; inter-replay fills
// evict L3 anyway, so don't pay for cache allocation).

typedef float f32x4 __attribute__((ext_vector_type(4)));

__global__ __launch_bounds__(256) void p1_eval_kernel(
    const f32x4* __restrict__ x4,   // 2 points per f32x4
    const float* __restrict__ w,    // 289 vertex weights
    f32x4*       __restrict__ out4, // 4 outputs per f32x4
    int n2)                         // number of out4 elements (4 points each)
{
    __shared__ f32x4 cw[256];       // per-cell {w00,w01,w10,w11}

    int t = threadIdx.x;            // doubles as cell id (16x16 cells)
    // --- 1) weight loads first (L2-hot, short latency) ---
    int ci = t >> 4, cj = t & 15;
    const float* wb = &w[ci * 17 + cj];
    float s00 = wb[0];
    float s01 = wb[1];
    float s10 = wb[17];
    float s11 = wb[18];

    // --- 2) x loads second (HBM, long latency; in flight during stage) ---
    int gid = blockIdx.x * 256 + t;
    bool valid = gid < n2;
    f32x4 va = (f32x4)(0.f);
    f32x4 vb = (f32x4)(0.f);
    if (valid) {
        va = __builtin_nontemporal_load(&x4[2 * gid]);
        vb = __builtin_nontemporal_load(&x4[2 * gid + 1]);
    }

    // --- 3) stage cell table, barrier ---
    f32x4 cv; cv.x = s00; cv.y = s01; cv.z = s10; cv.w = s11;
    cw[t] = cv;
    __syncthreads();

    if (!valid) return;

    float xs[4] = {va.x, va.z, vb.x, vb.z};
    float ys[4] = {va.y, va.w, vb.y, vb.w};
    float rs[4];
#pragma unroll
    for (int p = 0; p < 4; ++p) {
        float gx = xs[p] * 16.0f;
        float gy = ys[p] * 16.0f;
        int i0 = (int)gx;
        int j0 = (int)gy;
        bool boundary = ((float)i0 == gx && i0 >= 1) || ((float)j0 == gy && j0 >= 1);
        int i = min(i0, 15);
        int j = min(j0, 15);
        float fx = gx - (float)i;
        float fy = gy - (float)j;
        f32x4 cc = cw[(i << 4) | j];    // one ds_read_b128
        bool up = fy > fx;
        float s  = up ? fx      : fx - fy;
        float tt = up ? fy - fx : fy;
        float c1 = up ? cc.w    : cc.z;  // w11 : w10
        float c2 = up ? cc.y    : cc.w;  // w01 : w11
        float val = (1.0f - s - tt) * cc.x + s * c1 + tt * c2;
        rs[p] = boundary ? 0.0f : val;
    }
    f32x4 r; r.x = rs[0]; r.y = rs[1]; r.z = rs[2]; r.w = rs[3];
    __builtin_nontemporal_store(r, &out4[gid]);
}

extern "C" void kernel_launch(void* const* d_in, const int* in_sizes, int n_in,
                              void* d_out, int out_size, void* d_ws, size_t ws_size,
                              hipStream_t stream) {
    // inputs: x (8,262144,2) f32, weight (289,) f32, tri_A, Minv, bbox, dofs (unused)
    const f32x4* x4 = (const f32x4*)d_in[0];
    const float* w  = (const float*)d_in[1];
    f32x4* out4 = (f32x4*)d_out;

    int n_floats = in_sizes[0];      // 8*262144*2 = 4,194,304
    int n4 = n_floats / 4;           // 1,048,576 f32x4s (2 points each)
    int n2 = n4 / 2;                 // 524,288 threads, 4 points each
    int blocks = (n2 + 255) / 256;   // 2048

    p1_eval_kernel<<<blocks, 256, 0, stream>>>(x4, w, out4, n2);
}